// Round 1
// baseline (1211.936 us; speedup 1.0000x reference)
//
#include <hip/hip_runtime.h>

#define H 128
#define ND 4000
#define NPN 19000
#define NCN 1000
#define NLAYERS 2
#define NB 30000
#define E_DP 200000
#define E_PP 300000
#define E_CP 150000

// ---------------- wave reductions (wave64) ----------------
static __device__ __forceinline__ float wred_sum(float v) {
#pragma unroll
  for (int off = 32; off; off >>= 1) v += __shfl_xor(v, off);
  return v;
}
static __device__ __forceinline__ float wred_max(float v) {
#pragma unroll
  for (int off = 32; off; off >>= 1) v = fmaxf(v, __shfl_xor(v, off));
  return v;
}

// ---------------- generic fp32 GEMM body ----------------
// C[M,N] = act(A[M,K] @ B[K,N] + bias). BM=BN=128, BK=16, 256 thr, 8x8/thread.
// Requires: K % 16 == 0, N % 128 == 0. M guarded.
__device__ __forceinline__ void gemm_body(
    const float* __restrict__ A, const float* __restrict__ B, float* __restrict__ C,
    int M, int N, int K, const float* __restrict__ bias, int do_relu,
    int m0, int n0)
{
  __shared__ float As[16][132];
  __shared__ float Bs[16][132];
  const int t = threadIdx.x;
  const int tm = t >> 4;
  const int tn = t & 15;
  float acc[8][8];
#pragma unroll
  for (int i = 0; i < 8; ++i)
#pragma unroll
    for (int j = 0; j < 8; ++j) acc[i][j] = 0.f;

  const int arow = t >> 1;          // 0..127
  const int ak   = (t & 1) << 3;    // 0 or 8
  const int brow = t >> 4;          // 0..15
  const int bc   = (t & 15) << 3;   // 0..120
  const int grA = m0 + arow;
  const float* ap = A + (size_t)grA * K + ak;
  const float* bp = B + (size_t)brow * N + n0 + bc;

  for (int k0 = 0; k0 < K; k0 += 16) {
    float4 a0, a1;
    if (grA < M) {
      const float* p = ap + k0;
      a0 = *(const float4*)p;
      a1 = *(const float4*)(p + 4);
    } else {
      a0 = make_float4(0.f, 0.f, 0.f, 0.f); a1 = a0;
    }
    const float* q = bp + (size_t)k0 * N;
    float4 b0 = *(const float4*)q;
    float4 b1 = *(const float4*)(q + 4);
    __syncthreads();
    As[ak + 0][arow] = a0.x; As[ak + 1][arow] = a0.y;
    As[ak + 2][arow] = a0.z; As[ak + 3][arow] = a0.w;
    As[ak + 4][arow] = a1.x; As[ak + 5][arow] = a1.y;
    As[ak + 6][arow] = a1.z; As[ak + 7][arow] = a1.w;
    *(float4*)&Bs[brow][bc]     = b0;
    *(float4*)&Bs[brow][bc + 4] = b1;
    __syncthreads();
#pragma unroll
    for (int kk = 0; kk < 16; ++kk) {
      float av[8], bv[8];
      *(float4*)&av[0] = *(const float4*)&As[kk][tm * 8];
      *(float4*)&av[4] = *(const float4*)&As[kk][tm * 8 + 4];
      *(float4*)&bv[0] = *(const float4*)&Bs[kk][tn * 8];
      *(float4*)&bv[4] = *(const float4*)&Bs[kk][tn * 8 + 4];
#pragma unroll
      for (int i = 0; i < 8; ++i)
#pragma unroll
        for (int j = 0; j < 8; ++j)
          acc[i][j] = fmaf(av[i], bv[j], acc[i][j]);
    }
  }
  float bb[8];
#pragma unroll
  for (int j = 0; j < 8; ++j) bb[j] = bias ? bias[n0 + tn * 8 + j] : 0.f;
#pragma unroll
  for (int i = 0; i < 8; ++i) {
    int gr = m0 + tm * 8 + i;
    if (gr < M) {
      float o[8];
#pragma unroll
      for (int j = 0; j < 8; ++j) {
        float v = acc[i][j] + bb[j];
        o[j] = do_relu ? fmaxf(v, 0.f) : v;
      }
      float* cp = C + (size_t)gr * N + n0 + tn * 8;
      *(float4*)cp       = *(float4*)&o[0];
      *(float4*)(cp + 4) = *(float4*)&o[4];
    }
  }
}

__global__ __launch_bounds__(256) void k_gemm(
    const float* __restrict__ A, const float* __restrict__ B, float* __restrict__ C,
    int M, int N, int K, const float* __restrict__ bias, int do_relu)
{
  gemm_body(A, B, C, M, N, K, bias, do_relu, blockIdx.x * 128, blockIdx.y * 128);
}

struct GemmBatch { const float* A[5]; const float* B[5]; float* Cp[5]; int M[5]; };
__global__ __launch_bounds__(256) void k_gemm_h5(GemmBatch g) {
  int rel = blockIdx.y;
  int m0 = blockIdx.x * 128;
  if (m0 >= g.M[rel]) return;
  gemm_body(g.A[rel], g.B[rel], g.Cp[rel], g.M[rel], H, H, nullptr, 0, m0, 0);
}

// ---------------- wd = W @ a_dst ----------------
struct WdArgs { const float* W[5]; const float* ad[5]; float* wd[5]; };
__global__ __launch_bounds__(128) void k_wd5(WdArgs a) {
  int rel = blockIdx.x;
  int k = threadIdx.x;
  const float* Wp = a.W[rel];
  const float* ad = a.ad[rel];
  float s = 0.f;
#pragma unroll 4
  for (int j = 0; j < H; ++j) s = fmaf(Wp[k * H + j], ad[j], s);
  a.wd[rel][k] = s;
}

// ---------------- row dot: out[i] = X[i,:] . v ----------------
struct RowdotArgs { const float* X[10]; const float* v[10]; float* out[10]; int M[10]; };
__global__ __launch_bounds__(256) void k_rowdot10(RowdotArgs a) {
  int seg = blockIdx.y;
  int row = blockIdx.x * 4 + (threadIdx.x >> 6);
  if (row >= a.M[seg]) return;
  int lane = threadIdx.x & 63;
  const float* x = a.X[seg] + (size_t)row * H;
  const float* v = a.v[seg];
  float s = x[lane] * v[lane] + x[64 + lane] * v[64 + lane];
  s = wred_sum(s);
  if (!lane) a.out[seg][row] = s;
}

// ---------------- CSR build ----------------
struct CsrArgs {
  const int* src[5]; const int* dst[5];
  int E[5]; int loopbase[5]; int n[5];
  int* cnt[5]; int* cur[5]; int* starts[5]; int* csr[5];
};
__global__ __launch_bounds__(256) void k_count5(CsrArgs a) {
  int rel = blockIdx.y;
  int e = blockIdx.x * 256 + threadIdx.x;
  if (e >= a.E[rel]) return;
  int d = (e >= a.loopbase[rel]) ? (e - a.loopbase[rel]) : a.dst[rel][e];
  atomicAdd(&a.cnt[rel][d], 1);
}
__global__ __launch_bounds__(256) void k_scan5(CsrArgs a) {
  int rel = blockIdx.x;
  int n = a.n[rel];
  const int* cnt = a.cnt[rel];
  int* st = a.starts[rel];
  int* cu = a.cur[rel];
  __shared__ int part[256];
  int t = threadIdx.x;
  int stripe = (n + 255) / 256;
  int lo = t * stripe;
  int hi = lo + stripe; if (hi > n) hi = n;
  int s = 0;
  for (int i = lo; i < hi; ++i) s += cnt[i];
  part[t] = s;
  __syncthreads();
  if (t == 0) {
    int run = 0;
    for (int i = 0; i < 256; ++i) { int v = part[i]; part[i] = run; run += v; }
  }
  __syncthreads();
  int run = part[t];
  for (int i = lo; i < hi; ++i) { st[i] = run; cu[i] = run; run += cnt[i]; }
  if (lo < n && hi == n) st[n] = run;
}
__global__ __launch_bounds__(256) void k_fill5(CsrArgs a) {
  int rel = blockIdx.y;
  int e = blockIdx.x * 256 + threadIdx.x;
  if (e >= a.E[rel]) return;
  int d, s;
  if (e >= a.loopbase[rel]) { d = e - a.loopbase[rel]; s = d; }
  else { d = a.dst[rel][e]; s = a.src[rel][e]; }
  int pos = atomicAdd(&a.cur[rel][d], 1);
  a.csr[rel][pos] = s;
}

// ---------------- bias init / relu over the three node sets ----------------
__global__ __launch_bounds__(256) void k_init3(
    float* __restrict__ xpn, float* __restrict__ xdn, float* __restrict__ xcn,
    const float* __restrict__ bdp, const float* __restrict__ bpp, const float* __restrict__ bcp,
    const float* __restrict__ brdp, const float* __restrict__ brcp)
{
  int gid = blockIdx.x * 256 + threadIdx.x;
  int r = gid >> 7, j = gid & 127;
  if (r < NPN) xpn[gid] = bdp[j] + bpp[j] + bcp[j];
  else if (r < NPN + ND) xdn[(size_t)(r - NPN) * H + j] = brdp[j];
  else if (r < NPN + ND + NCN) xcn[(size_t)(r - NPN - ND) * H + j] = brcp[j];
}
__global__ __launch_bounds__(256) void k_relu3(
    float* __restrict__ xpn, float* __restrict__ xdn, float* __restrict__ xcn)
{
  int gid = blockIdx.x * 256 + threadIdx.x;
  int r = gid >> 7, j = gid & 127;
  if (r < NPN) xpn[gid] = fmaxf(xpn[gid], 0.f);
  else if (r < NPN + ND) { size_t o = (size_t)(r - NPN) * H + j; xdn[o] = fmaxf(xdn[o], 0.f); }
  else if (r < NPN + ND + NCN) { size_t o = (size_t)(r - NPN - ND) * H + j; xcn[o] = fmaxf(xcn[o], 0.f); }
}

// ---------------- GAT softmax + aggregation: one wave per dst node ----------------
struct AggArgs {
  const int* csr[5]; const int* starts[5];
  const float* ss[5]; const float* sd[5]; const float* hs[5];
  float* out[5]; int ndst[5];
};
__global__ __launch_bounds__(256) void k_agg5(AggArgs a) {
  int rel = blockIdx.y;
  int d = blockIdx.x * 4 + (threadIdx.x >> 6);
  if (d >= a.ndst[rel]) return;
  int lane = threadIdx.x & 63;
  int s0 = a.starts[rel][d], s1 = a.starts[rel][d + 1];
  int deg = s1 - s0;
  if (deg == 0) return;
  const int* cs = a.csr[rel] + s0;
  const float* ssp = a.ss[rel];
  float sdv = a.sd[rel][d];
  float m = -3.0e38f;
  for (int i = lane; i < deg; i += 64) {
    float e = ssp[cs[i]] + sdv;
    e = e > 0.f ? e : 0.2f * e;
    m = fmaxf(m, e);
  }
  m = wred_max(m);
  float ps = 0.f;
  for (int i = lane; i < deg; i += 64) {
    float e = ssp[cs[i]] + sdv;
    e = e > 0.f ? e : 0.2f * e;
    ps += __expf(e - m);
  }
  ps = wred_sum(ps);
  float inv = 1.f / ps;
  const float* hsp = a.hs[rel];
  float acc0 = 0.f, acc1 = 0.f;
  for (int i = 0; i < deg; ++i) {
    int s = cs[i];
    float e = ssp[s] + sdv;
    e = e > 0.f ? e : 0.2f * e;
    float al = __expf(e - m) * inv;
    const float* hr = hsp + (size_t)s * H;
    acc0 = fmaf(al, hr[lane], acc0);
    acc1 = fmaf(al, hr[64 + lane], acc1);
  }
  atomicAdd(&a.out[rel][(size_t)d * H + lane], acc0);
  atomicAdd(&a.out[rel][(size_t)d * H + 64 + lane], acc1);
}

// ---------------- readout ----------------
__global__ __launch_bounds__(256) void k_invnorm(
    const float* __restrict__ xd, const float* __restrict__ xc,
    float* __restrict__ invd, float* __restrict__ invc)
{
  int row = blockIdx.x * 4 + (threadIdx.x >> 6);
  if (row >= ND + NCN) return;
  int lane = threadIdx.x & 63;
  const float* x = (row < ND) ? xd + (size_t)row * H : xc + (size_t)(row - ND) * H;
  float u = x[lane], v = x[64 + lane];
  float s = wred_sum(u * u + v * v);
  if (!lane) {
    float nv = fmaxf(sqrtf(s), 1e-12f);
    if (row < ND) invd[row] = 1.f / nv; else invc[row - ND] = 1.f / nv;
  }
}
__global__ __launch_bounds__(256) void k_make_hid(
    const float* __restrict__ xd, const float* __restrict__ xc,
    const float* __restrict__ invd, const float* __restrict__ invc,
    const int* __restrict__ d1, const int* __restrict__ d2, const int* __restrict__ ce,
    float* __restrict__ hid, int c0, int cn)
{
  int gid = blockIdx.x * 256 + threadIdx.x;
  if (gid >= cn * 384) return;
  int i = gid / 384, c = gid - i * 384;
  int gi = c0 + i;
  float v;
  if (c < 128)      { int r = d1[gi]; v = xd[(size_t)r * H + c]       * invd[r]; }
  else if (c < 256) { int r = d2[gi]; v = xd[(size_t)r * H + (c-128)] * invd[r]; }
  else              { int r = ce[gi]; v = xc[(size_t)r * H + (c-256)] * invc[r]; }
  hid[gid] = v;
}
__global__ __launch_bounds__(256) void k_mlp3(
    const float* __restrict__ h2, const float* __restrict__ W3, const float* __restrict__ b3,
    float* __restrict__ out, int cn, int c0)
{
  int row = blockIdx.x * 4 + (threadIdx.x >> 6);
  if (row >= cn) return;
  int lane = threadIdx.x & 63;
  const float* h = h2 + (size_t)row * 256;
  float o0 = 0.f, o1 = 0.f;
  for (int k = lane; k < 256; k += 64) {
    float v = h[k];
    o0 = fmaf(v, W3[2 * k], o0);
    o1 = fmaf(v, W3[2 * k + 1], o1);
  }
  o0 = wred_sum(o0);
  o1 = wred_sum(o1);
  if (!lane) {
    out[(size_t)(c0 + row) * 2]     = o0 + b3[0];
    out[(size_t)(c0 + row) * 2 + 1] = o1 + b3[1];
  }
}

// ---------------- host ----------------
extern "C" void kernel_launch(void* const* d_in, const int* in_sizes, int n_in,
                              void* d_out, int out_size, void* d_ws, size_t ws_size,
                              hipStream_t stream)
{
  const float* drug_emb    = (const float*)d_in[0];
  const float* protein_emb = (const float*)d_in[1];
  const float* cell_emb    = (const float*)d_in[2];
  // input order: dp(3..6), rdp(7..10), pp(11..14), cp(15..18), rcp(19..22)
  // internal rel order: 0=dp, 1=pp, 2=cp, 3=rdp, 4=rcp
  const int base_idx[5] = {3, 11, 15, 7, 19};
  const float *W_[5], *as_[5], *ad_[5], *b_[5];
  for (int r = 0; r < 5; ++r) {
    W_[r]  = (const float*)d_in[base_idx[r]];
    as_[r] = (const float*)d_in[base_idx[r] + 1];
    ad_[r] = (const float*)d_in[base_idx[r] + 2];
    b_[r]  = (const float*)d_in[base_idx[r] + 3];
  }
  const float* W1 = (const float*)d_in[23]; const float* b1 = (const float*)d_in[24];
  const float* W2 = (const float*)d_in[25]; const float* b2 = (const float*)d_in[26];
  const float* W3 = (const float*)d_in[27]; const float* b3 = (const float*)d_in[28];
  const int* src_dp = (const int*)d_in[29]; const int* dst_dp = (const int*)d_in[30];
  const int* src_pp = (const int*)d_in[31]; const int* dst_pp = (const int*)d_in[32];
  const int* src_cp = (const int*)d_in[33]; const int* dst_cp = (const int*)d_in[34];
  const int* drug1  = (const int*)d_in[35]; const int* drug2  = (const int*)d_in[36];
  const int* cellb  = (const int*)d_in[37];
  float* out = (float*)d_out;
  (void)in_sizes; (void)n_in; (void)out_size;

  char* wsb = (char*)d_ws;
  size_t off = 0;
  auto alloc = [&](size_t bytes) -> void* {
    void* p = wsb + off;
    off += (bytes + 255) & ~(size_t)255;
    return p;
  };
  float* xd[2] = {(float*)alloc((size_t)ND * H * 4), (float*)alloc((size_t)ND * H * 4)};
  float* xp[2] = {(float*)alloc((size_t)NPN * H * 4), (float*)alloc((size_t)NPN * H * 4)};
  float* xc[2] = {(float*)alloc((size_t)NCN * H * 4), (float*)alloc((size_t)NCN * H * 4)};
  const int Msrc[5] = {ND, NPN, NCN, NPN, NPN};
  const int Mdst[5] = {NPN, NPN, NPN, ND, NCN};
  const int Erel[5] = {E_DP, E_PP + NPN, E_CP, E_DP, E_CP};
  float* hs[5];  for (int r = 0; r < 5; ++r) hs[r]  = (float*)alloc((size_t)Msrc[r] * H * 4);
  float* ssb[5]; for (int r = 0; r < 5; ++r) ssb[r] = (float*)alloc((size_t)Msrc[r] * 4);
  float* sdb[5]; for (int r = 0; r < 5; ++r) sdb[r] = (float*)alloc((size_t)Mdst[r] * 4);
  float* wdb[5]; for (int r = 0; r < 5; ++r) wdb[r] = (float*)alloc(H * 4);
  int* cnt_all = (int*)alloc(62000 * 4);
  int* cur_all = (int*)alloc(62000 * 4);
  int* st_all  = (int*)alloc((62000 + 5) * 4);
  int *cntb[5], *curb[5], *stb[5];
  { int o = 0, o2 = 0;
    for (int r = 0; r < 5; ++r) {
      cntb[r] = cnt_all + o; curb[r] = cur_all + o; stb[r] = st_all + o2;
      o += Mdst[r]; o2 += Mdst[r] + 1;
    } }
  int* csrb[5]; for (int r = 0; r < 5; ++r) csrb[r] = (int*)alloc((size_t)Erel[r] * 4);
  float* invd = (float*)alloc(ND * 4);
  float* invc = (float*)alloc(NCN * 4);
  size_t fixed_end = off;
  size_t avail = ws_size > fixed_end ? ws_size - fixed_end : 0;
  long long cmax = (long long)(avail / 4) / 1412;
  int CH = cmax > NB ? NB : (int)cmax;
  CH &= ~255;
  if (CH < 256) CH = 256;
  float* hid = (float*)alloc((size_t)CH * 384 * 4);
  float* h1  = (float*)alloc((size_t)CH * 768 * 4);
  float* h2  = (float*)alloc((size_t)CH * 256 * 4);

  // init node features
  hipMemcpyAsync(xd[0], drug_emb,    (size_t)ND * H * 4, hipMemcpyDeviceToDevice, stream);
  hipMemcpyAsync(xp[0], protein_emb, (size_t)NPN * H * 4, hipMemcpyDeviceToDevice, stream);
  hipMemcpyAsync(xc[0], cell_emb,    (size_t)NCN * H * 4, hipMemcpyDeviceToDevice, stream);

  // CSR build (once; graph static across layers)
  hipMemsetAsync(cnt_all, 0, 62000 * 4, stream);
  CsrArgs ca;
  const int* srcA[5] = {src_dp, src_pp, src_cp, dst_dp, dst_cp};
  const int* dstA[5] = {dst_dp, dst_pp, dst_cp, src_dp, src_cp};
  const int loopb[5] = {0x7fffffff, E_PP, 0x7fffffff, 0x7fffffff, 0x7fffffff};
  for (int r = 0; r < 5; ++r) {
    ca.src[r] = srcA[r]; ca.dst[r] = dstA[r]; ca.E[r] = Erel[r];
    ca.loopbase[r] = loopb[r]; ca.n[r] = Mdst[r];
    ca.cnt[r] = cntb[r]; ca.cur[r] = curb[r]; ca.starts[r] = stb[r]; ca.csr[r] = csrb[r];
  }
  dim3 egrid((E_PP + NPN + 255) / 256, 5);
  k_count5<<<egrid, 256, 0, stream>>>(ca);
  k_scan5<<<5, 256, 0, stream>>>(ca);
  k_fill5<<<egrid, 256, 0, stream>>>(ca);

  int cur = 0;
  for (int l = 0; l < NLAYERS; ++l) {
    int nxt = 1 - cur;
    k_init3<<<12000, 256, 0, stream>>>(xp[nxt], xd[nxt], xc[nxt],
        b_[0] + l * H, b_[1] + l * H, b_[2] + l * H, b_[3] + l * H, b_[4] + l * H);
    const float* xsrc[5] = {xd[cur], xp[cur], xc[cur], xp[cur], xp[cur]};
    const float* xdst[5] = {xp[cur], xp[cur], xp[cur], xd[cur], xc[cur]};
    GemmBatch gb;
    for (int r = 0; r < 5; ++r) {
      gb.A[r] = xsrc[r]; gb.B[r] = W_[r] + (size_t)l * H * H; gb.Cp[r] = hs[r]; gb.M[r] = Msrc[r];
    }
    k_gemm_h5<<<dim3((NPN + 127) / 128, 5), 256, 0, stream>>>(gb);
    WdArgs wa;
    for (int r = 0; r < 5; ++r) { wa.W[r] = W_[r] + (size_t)l * H * H; wa.ad[r] = ad_[r] + l * H; wa.wd[r] = wdb[r]; }
    k_wd5<<<5, 128, 0, stream>>>(wa);
    RowdotArgs ra;
    for (int r = 0; r < 5; ++r) {
      ra.X[r] = hs[r]; ra.v[r] = as_[r] + l * H; ra.out[r] = ssb[r]; ra.M[r] = Msrc[r];
      ra.X[5 + r] = xdst[r]; ra.v[5 + r] = wdb[r]; ra.out[5 + r] = sdb[r]; ra.M[5 + r] = Mdst[r];
    }
    k_rowdot10<<<dim3((NPN + 3) / 4, 10), 256, 0, stream>>>(ra);
    AggArgs aa;
    float* outs[5] = {xp[nxt], xp[nxt], xp[nxt], xd[nxt], xc[nxt]};
    for (int r = 0; r < 5; ++r) {
      aa.csr[r] = csrb[r]; aa.starts[r] = stb[r]; aa.ss[r] = ssb[r]; aa.sd[r] = sdb[r];
      aa.hs[r] = hs[r]; aa.out[r] = outs[r]; aa.ndst[r] = Mdst[r];
    }
    k_agg5<<<dim3((NPN + 3) / 4, 5), 256, 0, stream>>>(aa);
    k_relu3<<<12000, 256, 0, stream>>>(xp[nxt], xd[nxt], xc[nxt]);
    cur = nxt;
  }

  k_invnorm<<<(ND + NCN + 3) / 4, 256, 0, stream>>>(xd[cur], xc[cur], invd, invc);
  for (int c0 = 0; c0 < NB; c0 += CH) {
    int cn = (NB - c0 < CH) ? (NB - c0) : CH;
    k_make_hid<<<((size_t)cn * 384 + 255) / 256, 256, 0, stream>>>(
        xd[cur], xc[cur], invd, invc, drug1, drug2, cellb, hid, c0, cn);
    k_gemm<<<dim3((cn + 127) / 128, 6), 256, 0, stream>>>(hid, W1, h1, cn, 768, 384, b1, 1);
    k_gemm<<<dim3((cn + 127) / 128, 2), 256, 0, stream>>>(h1, W2, h2, cn, 256, 768, b2, 1);
    k_mlp3<<<(cn + 3) / 4, 256, 0, stream>>>(h2, W3, b3, out, cn, c0);
  }
}

// Round 2
// 542.205 us; speedup vs baseline: 2.2352x; 2.2352x over previous
//
#include <hip/hip_runtime.h>
#include <hip/hip_bf16.h>

#define H 128
#define ND 4000
#define NPN 19000
#define NCN 1000
#define NLAYERS 2
#define NB 30000
#define E_DP 200000
#define E_PP 300000
#define E_CP 150000

typedef __bf16 bf16_t;
typedef bf16_t bf16x8 __attribute__((ext_vector_type(8)));
typedef float f32x4 __attribute__((ext_vector_type(4)));

static __device__ __forceinline__ float wred_sum(float v) {
#pragma unroll
  for (int off = 32; off; off >>= 1) v += __shfl_xor(v, off);
  return v;
}
static __device__ __forceinline__ float wred_max(float v) {
#pragma unroll
  for (int off = 32; off; off >>= 1) v = fmaxf(v, __shfl_xor(v, off));
  return v;
}
static __device__ __forceinline__ float bflo(unsigned u) { return __uint_as_float(u << 16); }
static __device__ __forceinline__ float bfhi(unsigned u) { return __uint_as_float(u & 0xffff0000u); }
static __device__ __forceinline__ unsigned packbf(float v0, float v1) {
  union { bf16_t b; unsigned short u; } a, b;
  a.b = (bf16_t)v0; b.b = (bf16_t)v1;
  return (unsigned)a.u | ((unsigned)b.u << 16);
}

// ================= bf16 MFMA GEMM =================
// A [M,K] bf16 row-major, Bt [N,K] bf16 (B transposed), C [M,N] bf16.
// BM=BN=128, BK=32, 256 threads (4 waves, 2x2), 16x16x32 MFMA, 4x4 frags/wave.
// LDS tiles [128 rows][32 k] with 16B-chunk XOR swizzle c' = c ^ ((r>>1)&3).
// Requires K%32==0, N%128==0. M guarded (A row clamp + C guard).
__device__ __forceinline__ void mfma_gemm_body(
    const bf16_t* __restrict__ A, const bf16_t* __restrict__ Bt, bf16_t* __restrict__ C,
    int M, int N, int K, const float* __restrict__ bias, int do_relu, int m0, int n0)
{
  __shared__ char As[128 * 64];
  __shared__ char Bs[128 * 64];
  const int t = threadIdx.x;
  const int lane = t & 63;
  const int wid = t >> 6;
  const int wr = wid >> 1, wc = wid & 1;
  f32x4 acc[4][4];
#pragma unroll
  for (int mi = 0; mi < 4; ++mi)
#pragma unroll
    for (int ni = 0; ni < 4; ++ni) acc[mi][ni] = (f32x4){0.f, 0.f, 0.f, 0.f};

  // staging mapping: thread t -> rows sr, 64+sr ; 16B chunk sc
  const int sr = t >> 2;
  const int sc = t & 3;
  int ra0 = m0 + sr;      if (ra0 >= M) ra0 = M - 1;
  int ra1 = m0 + 64 + sr; if (ra1 >= M) ra1 = M - 1;
  const char* gA0 = (const char*)(A + (size_t)ra0 * K) + sc * 16;
  const char* gA1 = (const char*)(A + (size_t)ra1 * K) + sc * 16;
  const char* gB0 = (const char*)(Bt + (size_t)(n0 + sr) * K) + sc * 16;
  const char* gB1 = (const char*)(Bt + (size_t)(n0 + 64 + sr) * K) + sc * 16;
  const int wo0 = sr * 64        + ((sc ^ ((sr >> 1) & 3)) << 4);
  const int wo1 = (64 + sr) * 64 + ((sc ^ (((64 + sr) >> 1) & 3)) << 4);

  int aoff[4], boff[4];
#pragma unroll
  for (int mi = 0; mi < 4; ++mi) {
    int r = wr * 64 + mi * 16 + (lane & 15);
    aoff[mi] = r * 64 + ((((lane >> 4)) ^ ((r >> 1) & 3)) << 4);
  }
#pragma unroll
  for (int ni = 0; ni < 4; ++ni) {
    int r = wc * 64 + ni * 16 + (lane & 15);
    boff[ni] = r * 64 + ((((lane >> 4)) ^ ((r >> 1) & 3)) << 4);
  }

  for (int k0 = 0; k0 < K; k0 += 32) {
    const size_t kb = (size_t)k0 * 2;
    uint4 a0 = *(const uint4*)(gA0 + kb);
    uint4 a1 = *(const uint4*)(gA1 + kb);
    uint4 b0 = *(const uint4*)(gB0 + kb);
    uint4 b1 = *(const uint4*)(gB1 + kb);
    __syncthreads();
    *(uint4*)(As + wo0) = a0; *(uint4*)(As + wo1) = a1;
    *(uint4*)(Bs + wo0) = b0; *(uint4*)(Bs + wo1) = b1;
    __syncthreads();
    bf16x8 av[4], bv[4];
#pragma unroll
    for (int mi = 0; mi < 4; ++mi) av[mi] = *(const bf16x8*)(As + aoff[mi]);
#pragma unroll
    for (int ni = 0; ni < 4; ++ni) bv[ni] = *(const bf16x8*)(Bs + boff[ni]);
#pragma unroll
    for (int mi = 0; mi < 4; ++mi)
#pragma unroll
      for (int ni = 0; ni < 4; ++ni)
        acc[mi][ni] = __builtin_amdgcn_mfma_f32_16x16x32_bf16(av[mi], bv[ni], acc[mi][ni], 0, 0, 0);
  }

  // epilogue: C/D layout col=lane&15, row=(lane>>4)*4+reg  [m89]
  const int col0 = lane & 15;
  const int rsub = (lane >> 4) * 4;
#pragma unroll
  for (int mi = 0; mi < 4; ++mi) {
#pragma unroll
    for (int ni = 0; ni < 4; ++ni) {
      int c = n0 + wc * 64 + ni * 16 + col0;
      float bb = bias ? bias[c] : 0.f;
#pragma unroll
      for (int rg = 0; rg < 4; ++rg) {
        int r = m0 + wr * 64 + mi * 16 + rsub + rg;
        if (r < M) {
          float v = acc[mi][ni][rg] + bb;
          if (do_relu) v = fmaxf(v, 0.f);
          C[(size_t)r * N + c] = (bf16_t)v;
        }
      }
    }
  }
}

__global__ __launch_bounds__(256) void k_gemm_bf(
    const bf16_t* __restrict__ A, const bf16_t* __restrict__ Bt, bf16_t* __restrict__ C,
    int M, int N, int K, const float* __restrict__ bias, int do_relu)
{
  mfma_gemm_body(A, Bt, C, M, N, K, bias, do_relu, blockIdx.x * 128, blockIdx.y * 128);
}

struct Gemm5 { const bf16_t* A[5]; const bf16_t* Bt[5]; bf16_t* Cp[5]; int M[5]; };
__global__ __launch_bounds__(256) void k_gemm_h5(Gemm5 g) {
  int rel = blockIdx.y;
  int m0 = blockIdx.x * 128;
  if (m0 >= g.M[rel]) return;
  mfma_gemm_body(g.A[rel], g.Bt[rel], g.Cp[rel], g.M[rel], H, H, nullptr, 0, m0, 0);
}

// ================= conversions =================
__global__ __launch_bounds__(256) void k_conv_emb(
    const float* __restrict__ xd, const float* __restrict__ xp, const float* __restrict__ xc,
    bf16_t* __restrict__ od, bf16_t* __restrict__ op, bf16_t* __restrict__ oc)
{
  int i = blockIdx.x * 256 + threadIdx.x;
  const int SD = ND * H, SP = NPN * H, SC = NCN * H;
  if (i < SD) od[i] = (bf16_t)xd[i];
  else if (i < SD + SP) op[i - SD] = (bf16_t)xp[i - SD];
  else if (i < SD + SP + SC) oc[i - SD - SP] = (bf16_t)xc[i - SD - SP];
}

// batched transpose-convert: dst[n*K+k] = bf16(src[k*N+n])
struct TCBatch { const float* src[12]; bf16_t* dst[12]; int K[12]; int N[12]; };
__global__ __launch_bounds__(256) void k_tconv(TCBatch a) {
  int m = blockIdx.y;
  int i = blockIdx.x * 256 + threadIdx.x;
  int K = a.K[m], N = a.N[m];
  if (i >= K * N) return;
  int n = i / K, k = i - n * K;
  a.dst[m][i] = (bf16_t)a.src[m][(size_t)k * N + n];
}

// ---------------- wd = W @ a_dst (fp32) ----------------
struct WdArgs { const float* W[5]; const float* ad[5]; float* wd[5]; };
__global__ __launch_bounds__(128) void k_wd5(WdArgs a) {
  int rel = blockIdx.x;
  int k = threadIdx.x;
  const float* Wp = a.W[rel];
  const float* ad = a.ad[rel];
  float s = 0.f;
#pragma unroll 4
  for (int j = 0; j < H; ++j) s = fmaf(Wp[k * H + j], ad[j], s);
  a.wd[rel][k] = s;
}

// ---------------- row dot (bf16 X, fp32 v) ----------------
struct Rd10 { const bf16_t* X[10]; const float* v[10]; float* out[10]; int M[10]; };
__global__ __launch_bounds__(256) void k_rowdot10(Rd10 a) {
  int seg = blockIdx.y;
  int row = blockIdx.x * 4 + (threadIdx.x >> 6);
  if (row >= a.M[seg]) return;
  int lane = threadIdx.x & 63;
  unsigned u = *(const unsigned*)(a.X[seg] + (size_t)row * H + lane * 2);
  const float* v = a.v[seg];
  float s = bflo(u) * v[2 * lane] + bfhi(u) * v[2 * lane + 1];
  s = wred_sum(s);
  if (!lane) a.out[seg][row] = s;
}

// ---------------- CSR build ----------------
struct CsrArgs {
  const int* src[5]; const int* dst[5];
  int E[5]; int loopbase[5]; int n[5];
  int* cnt[5]; int* cur[5]; int* starts[5]; int* csr[5];
};
__global__ __launch_bounds__(256) void k_count5(CsrArgs a) {
  int rel = blockIdx.y;
  int e = blockIdx.x * 256 + threadIdx.x;
  if (e >= a.E[rel]) return;
  int d = (e >= a.loopbase[rel]) ? (e - a.loopbase[rel]) : a.dst[rel][e];
  atomicAdd(&a.cnt[rel][d], 1);
}
__global__ __launch_bounds__(256) void k_scan5(CsrArgs a) {
  int rel = blockIdx.x;
  int n = a.n[rel];
  const int* cnt = a.cnt[rel];
  int* st = a.starts[rel];
  int* cu = a.cur[rel];
  __shared__ int part[256];
  int t = threadIdx.x;
  int stripe = (n + 255) / 256;
  int lo = t * stripe;
  int hi = lo + stripe; if (hi > n) hi = n;
  int s = 0;
  for (int i = lo; i < hi; ++i) s += cnt[i];
  part[t] = s;
  __syncthreads();
  if (t == 0) {
    int run = 0;
    for (int i = 0; i < 256; ++i) { int v = part[i]; part[i] = run; run += v; }
  }
  __syncthreads();
  int run = part[t];
  for (int i = lo; i < hi; ++i) { st[i] = run; cu[i] = run; run += cnt[i]; }
  if (lo < n && hi == n) st[n] = run;
}
__global__ __launch_bounds__(256) void k_fill5(CsrArgs a) {
  int rel = blockIdx.y;
  int e = blockIdx.x * 256 + threadIdx.x;
  if (e >= a.E[rel]) return;
  int d, s;
  if (e >= a.loopbase[rel]) { d = e - a.loopbase[rel]; s = d; }
  else { d = a.dst[rel][e]; s = a.src[rel][e]; }
  int pos = atomicAdd(&a.cur[rel][d], 1);
  a.csr[rel][pos] = s;
}

// ---------------- fused GAT softmax+aggregate+bias+relu ----------------
// class 0: protein (rels 0,1,2), 1: drug (rel 3), 2: cell (rel 4).
// One wave per dst node; 4 edges in flight (16 lanes x 16B per h-row).
struct Agg3 {
  const int* csr[5]; const int* starts[5];
  const float* ss[5]; const float* sd[5]; const bf16_t* hs[5];
  const float* bias[5];
  bf16_t* out[3]; int ndst[3];
};
__global__ __launch_bounds__(256) void k_agg3(Agg3 a) {
  int cls = blockIdx.y;
  int d = blockIdx.x * 4 + (threadIdx.x >> 6);
  if (d >= a.ndst[cls]) return;
  int lane = threadIdx.x & 63;
  int g = lane >> 4, j = lane & 15;
  float acc[8] = {0.f, 0.f, 0.f, 0.f, 0.f, 0.f, 0.f, 0.f};
  int r0 = (cls == 0) ? 0 : (cls == 1 ? 3 : 4);
  int nr = (cls == 0) ? 3 : 1;
  for (int rr = 0; rr < nr; ++rr) {
    int r = r0 + rr;
    int s0 = a.starts[r][d];
    int deg = a.starts[r][d + 1] - s0;
    if (!deg) continue;
    const int* cs = a.csr[r] + s0;
    const float* ssp = a.ss[r];
    float sdv = a.sd[r][d];
    float m = -3.0e38f;
    for (int i = lane; i < deg; i += 64) {
      float e = ssp[cs[i]] + sdv; e = e > 0.f ? e : 0.2f * e;
      m = fmaxf(m, e);
    }
    m = wred_max(m);
    float ps = 0.f;
    for (int i = lane; i < deg; i += 64) {
      float e = ssp[cs[i]] + sdv; e = e > 0.f ? e : 0.2f * e;
      ps += __expf(e - m);
    }
    ps = wred_sum(ps);
    float inv = 1.f / ps;
    const bf16_t* hsp = a.hs[r];
    for (int b = 0; b < deg; b += 4) {
      int i = b + g;
      float al = 0.f;
      uint4 U = make_uint4(0u, 0u, 0u, 0u);
      if (i < deg) {
        int s = cs[i];
        float e = ssp[s] + sdv; e = e > 0.f ? e : 0.2f * e;
        al = __expf(e - m) * inv;
        U = *(const uint4*)(hsp + (size_t)s * H + j * 8);
      }
      acc[0] = fmaf(al, bflo(U.x), acc[0]); acc[1] = fmaf(al, bfhi(U.x), acc[1]);
      acc[2] = fmaf(al, bflo(U.y), acc[2]); acc[3] = fmaf(al, bfhi(U.y), acc[3]);
      acc[4] = fmaf(al, bflo(U.z), acc[4]); acc[5] = fmaf(al, bfhi(U.z), acc[5]);
      acc[6] = fmaf(al, bflo(U.w), acc[6]); acc[7] = fmaf(al, bfhi(U.w), acc[7]);
    }
  }
#pragma unroll
  for (int e = 0; e < 8; ++e) {
    acc[e] += __shfl_xor(acc[e], 16);
    acc[e] += __shfl_xor(acc[e], 32);
  }
  if (g == 0) {
    float bs[8];
    const float* b0 = a.bias[r0];
#pragma unroll
    for (int e = 0; e < 8; ++e) bs[e] = b0[j * 8 + e];
    if (cls == 0) {
#pragma unroll
      for (int e = 0; e < 8; ++e) bs[e] += a.bias[1][j * 8 + e] + a.bias[2][j * 8 + e];
    }
    uint4 O;
    O.x = packbf(fmaxf(acc[0] + bs[0], 0.f), fmaxf(acc[1] + bs[1], 0.f));
    O.y = packbf(fmaxf(acc[2] + bs[2], 0.f), fmaxf(acc[3] + bs[3], 0.f));
    O.z = packbf(fmaxf(acc[4] + bs[4], 0.f), fmaxf(acc[5] + bs[5], 0.f));
    O.w = packbf(fmaxf(acc[6] + bs[6], 0.f), fmaxf(acc[7] + bs[7], 0.f));
    *(uint4*)(a.out[cls] + (size_t)d * H + j * 8) = O;
  }
}

// ---------------- readout ----------------
__global__ __launch_bounds__(256) void k_invnorm(
    const bf16_t* __restrict__ xd, const bf16_t* __restrict__ xc,
    float* __restrict__ invd, float* __restrict__ invc)
{
  int row = blockIdx.x * 4 + (threadIdx.x >> 6);
  if (row >= ND + NCN) return;
  int lane = threadIdx.x & 63;
  const bf16_t* x = (row < ND) ? xd + (size_t)row * H : xc + (size_t)(row - ND) * H;
  unsigned u = *(const unsigned*)(x + lane * 2);
  float av = bflo(u), bv = bfhi(u);
  float s = wred_sum(av * av + bv * bv);
  if (!lane) {
    float nv = fmaxf(sqrtf(s), 1e-12f);
    if (row < ND) invd[row] = 1.f / nv; else invc[row - ND] = 1.f / nv;
  }
}
__global__ __launch_bounds__(256) void k_make_hid(
    const bf16_t* __restrict__ xd, const bf16_t* __restrict__ xc,
    const float* __restrict__ invd, const float* __restrict__ invc,
    const int* __restrict__ d1, const int* __restrict__ d2, const int* __restrict__ ce,
    bf16_t* __restrict__ hid, int c0, int cn)
{
  int gid = blockIdx.x * 256 + threadIdx.x;     // one 16B chunk (8 feats)
  if (gid >= cn * 48) return;
  int i = gid / 48, c16 = gid - i * 48;
  int gi = c0 + i;
  int sel = c16 >> 4;
  int jb = (c16 & 15) * 8;
  int rrow; const bf16_t* xs; float sc;
  if (sel == 0)      { rrow = d1[gi]; xs = xd; sc = invd[rrow]; }
  else if (sel == 1) { rrow = d2[gi]; xs = xd; sc = invd[rrow]; }
  else               { rrow = ce[gi]; xs = xc; sc = invc[rrow]; }
  uint4 U = *(const uint4*)(xs + (size_t)rrow * H + jb);
  uint4 O;
  O.x = packbf(bflo(U.x) * sc, bfhi(U.x) * sc);
  O.y = packbf(bflo(U.y) * sc, bfhi(U.y) * sc);
  O.z = packbf(bflo(U.z) * sc, bfhi(U.z) * sc);
  O.w = packbf(bflo(U.w) * sc, bfhi(U.w) * sc);
  *(uint4*)(hid + (size_t)i * 384 + c16 * 8) = O;
}
__global__ __launch_bounds__(256) void k_mlp3(
    const bf16_t* __restrict__ h2, const float* __restrict__ W3, const float* __restrict__ b3,
    float* __restrict__ out, int cn, int c0)
{
  int row = blockIdx.x * 4 + (threadIdx.x >> 6);
  if (row >= cn) return;
  int lane = threadIdx.x & 63;
  uint2 U = *(const uint2*)(h2 + (size_t)row * 256 + lane * 4);
  float v0 = bflo(U.x), v1 = bfhi(U.x), v2 = bflo(U.y), v3 = bfhi(U.y);
  const float* w = W3 + 8 * lane;
  float4 wa = *(const float4*)w;
  float4 wb = *(const float4*)(w + 4);
  float o0 = v0 * wa.x + v1 * wa.z + v2 * wb.x + v3 * wb.z;
  float o1 = v0 * wa.y + v1 * wa.w + v2 * wb.y + v3 * wb.w;
  o0 = wred_sum(o0);
  o1 = wred_sum(o1);
  if (!lane) {
    out[(size_t)(c0 + row) * 2]     = o0 + b3[0];
    out[(size_t)(c0 + row) * 2 + 1] = o1 + b3[1];
  }
}

// ================= host =================
extern "C" void kernel_launch(void* const* d_in, const int* in_sizes, int n_in,
                              void* d_out, int out_size, void* d_ws, size_t ws_size,
                              hipStream_t stream)
{
  (void)in_sizes; (void)n_in; (void)out_size;
  const float* drug_emb    = (const float*)d_in[0];
  const float* protein_emb = (const float*)d_in[1];
  const float* cell_emb    = (const float*)d_in[2];
  // internal rel order: 0=dp, 1=pp, 2=cp, 3=rdp, 4=rcp
  const int base_idx[5] = {3, 11, 15, 7, 19};
  const float *W_[5], *as_[5], *ad_[5], *b_[5];
  for (int r = 0; r < 5; ++r) {
    W_[r]  = (const float*)d_in[base_idx[r]];
    as_[r] = (const float*)d_in[base_idx[r] + 1];
    ad_[r] = (const float*)d_in[base_idx[r] + 2];
    b_[r]  = (const float*)d_in[base_idx[r] + 3];
  }
  const float* W1 = (const float*)d_in[23]; const float* b1 = (const float*)d_in[24];
  const float* W2 = (const float*)d_in[25]; const float* b2 = (const float*)d_in[26];
  const float* W3 = (const float*)d_in[27]; const float* b3 = (const float*)d_in[28];
  const int* src_dp = (const int*)d_in[29]; const int* dst_dp = (const int*)d_in[30];
  const int* src_pp = (const int*)d_in[31]; const int* dst_pp = (const int*)d_in[32];
  const int* src_cp = (const int*)d_in[33]; const int* dst_cp = (const int*)d_in[34];
  const int* drug1  = (const int*)d_in[35]; const int* drug2  = (const int*)d_in[36];
  const int* cellb  = (const int*)d_in[37];
  float* out = (float*)d_out;

  char* wsb = (char*)d_ws;
  size_t off = 0;
  auto alloc = [&](size_t bytes) -> void* {
    void* p = wsb + off;
    off += (bytes + 255) & ~(size_t)255;
    return p;
  };
  bf16_t* xdb[2] = {(bf16_t*)alloc((size_t)ND * H * 2),  (bf16_t*)alloc((size_t)ND * H * 2)};
  bf16_t* xpb[2] = {(bf16_t*)alloc((size_t)NPN * H * 2), (bf16_t*)alloc((size_t)NPN * H * 2)};
  bf16_t* xcb[2] = {(bf16_t*)alloc((size_t)NCN * H * 2), (bf16_t*)alloc((size_t)NCN * H * 2)};
  const int Msrc[5] = {ND, NPN, NCN, NPN, NPN};
  const int Mdst[5] = {NPN, NPN, NPN, ND, NCN};
  const int Erel[5] = {E_DP, E_PP + NPN, E_CP, E_DP, E_CP};
  bf16_t* hs[5];   for (int r = 0; r < 5; ++r) hs[r]  = (bf16_t*)alloc((size_t)Msrc[r] * H * 2);
  bf16_t* Wtb[5];  for (int r = 0; r < 5; ++r) Wtb[r] = (bf16_t*)alloc((size_t)NLAYERS * H * H * 2);
  bf16_t* W1t = (bf16_t*)alloc((size_t)768 * 384 * 2);
  bf16_t* W2t = (bf16_t*)alloc((size_t)256 * 768 * 2);
  float* ssb[5]; for (int r = 0; r < 5; ++r) ssb[r] = (float*)alloc((size_t)Msrc[r] * 4);
  float* sdb[5]; for (int r = 0; r < 5; ++r) sdb[r] = (float*)alloc((size_t)Mdst[r] * 4);
  float* wdb[5]; for (int r = 0; r < 5; ++r) wdb[r] = (float*)alloc(H * 4);
  int* cnt_all = (int*)alloc(62000 * 4);
  int* cur_all = (int*)alloc(62000 * 4);
  int* st_all  = (int*)alloc((62000 + 5) * 4);
  int *cntb[5], *curb[5], *stb[5];
  { int o = 0, o2 = 0;
    for (int r = 0; r < 5; ++r) {
      cntb[r] = cnt_all + o; curb[r] = cur_all + o; stb[r] = st_all + o2;
      o += Mdst[r]; o2 += Mdst[r] + 1;
    } }
  int* csrb[5]; for (int r = 0; r < 5; ++r) csrb[r] = (int*)alloc((size_t)Erel[r] * 4);
  float* invd = (float*)alloc(ND * 4);
  float* invc = (float*)alloc(NCN * 4);
  size_t fixed_end = off;
  size_t avail = ws_size > fixed_end ? ws_size - fixed_end : 0;
  long long cmax = (long long)avail / 2816;
  int CH = cmax > NB ? NB : (int)cmax;
  CH &= ~255;
  if (CH < 256) CH = 256;
  bf16_t* hid = (bf16_t*)alloc((size_t)CH * 384 * 2);
  bf16_t* h1  = (bf16_t*)alloc((size_t)CH * 768 * 2);
  bf16_t* h2  = (bf16_t*)alloc((size_t)CH * 256 * 2);

  // conversions
  k_conv_emb<<<(ND * H + NPN * H + NCN * H + 255) / 256, 256, 0, stream>>>(
      drug_emb, protein_emb, cell_emb, xdb[0], xpb[0], xcb[0]);
  TCBatch tc;
  for (int r = 0; r < 5; ++r)
    for (int l = 0; l < 2; ++l) {
      int m = r * 2 + l;
      tc.src[m] = W_[r] + (size_t)l * H * H;
      tc.dst[m] = Wtb[r] + (size_t)l * H * H;
      tc.K[m] = H; tc.N[m] = H;
    }
  tc.src[10] = W1; tc.dst[10] = W1t; tc.K[10] = 384; tc.N[10] = 768;
  tc.src[11] = W2; tc.dst[11] = W2t; tc.K[11] = 768; tc.N[11] = 256;
  k_tconv<<<dim3((768 * 384 + 255) / 256, 12), 256, 0, stream>>>(tc);

  // CSR build
  hipMemsetAsync(cnt_all, 0, 62000 * 4, stream);
  CsrArgs ca;
  const int* srcA[5] = {src_dp, src_pp, src_cp, dst_dp, dst_cp};
  const int* dstA[5] = {dst_dp, dst_pp, dst_cp, src_dp, src_cp};
  const int loopb[5] = {0x7fffffff, E_PP, 0x7fffffff, 0x7fffffff, 0x7fffffff};
  for (int r = 0; r < 5; ++r) {
    ca.src[r] = srcA[r]; ca.dst[r] = dstA[r]; ca.E[r] = Erel[r];
    ca.loopbase[r] = loopb[r]; ca.n[r] = Mdst[r];
    ca.cnt[r] = cntb[r]; ca.cur[r] = curb[r]; ca.starts[r] = stb[r]; ca.csr[r] = csrb[r];
  }
  dim3 egrid((E_PP + NPN + 255) / 256, 5);
  k_count5<<<egrid, 256, 0, stream>>>(ca);
  k_scan5<<<5, 256, 0, stream>>>(ca);
  k_fill5<<<egrid, 256, 0, stream>>>(ca);

  int cur = 0;
  for (int l = 0; l < NLAYERS; ++l) {
    int nxt = 1 - cur;
    const bf16_t* xsrc[5] = {xdb[cur], xpb[cur], xcb[cur], xpb[cur], xpb[cur]};
    const bf16_t* xdst[5] = {xpb[cur], xpb[cur], xpb[cur], xdb[cur], xcb[cur]};
    Gemm5 gb;
    for (int r = 0; r < 5; ++r) {
      gb.A[r] = xsrc[r]; gb.Bt[r] = Wtb[r] + (size_t)l * H * H; gb.Cp[r] = hs[r]; gb.M[r] = Msrc[r];
    }
    k_gemm_h5<<<dim3((NPN + 127) / 128, 5), 256, 0, stream>>>(gb);
    WdArgs wa;
    for (int r = 0; r < 5; ++r) {
      wa.W[r] = W_[r] + (size_t)l * H * H; wa.ad[r] = ad_[r] + l * H; wa.wd[r] = wdb[r];
    }
    k_wd5<<<5, 128, 0, stream>>>(wa);
    Rd10 ra;
    for (int r = 0; r < 5; ++r) {
      ra.X[r] = hs[r]; ra.v[r] = as_[r] + l * H; ra.out[r] = ssb[r]; ra.M[r] = Msrc[r];
      ra.X[5 + r] = xdst[r]; ra.v[5 + r] = wdb[r]; ra.out[5 + r] = sdb[r]; ra.M[5 + r] = Mdst[r];
    }
    k_rowdot10<<<dim3((NPN + 3) / 4, 10), 256, 0, stream>>>(ra);
    Agg3 aa;
    for (int r = 0; r < 5; ++r) {
      aa.csr[r] = csrb[r]; aa.starts[r] = stb[r]; aa.ss[r] = ssb[r]; aa.sd[r] = sdb[r];
      aa.hs[r] = hs[r]; aa.bias[r] = b_[r] + l * H;
    }
    aa.out[0] = xpb[nxt]; aa.out[1] = xdb[nxt]; aa.out[2] = xcb[nxt];
    aa.ndst[0] = NPN; aa.ndst[1] = ND; aa.ndst[2] = NCN;
    k_agg3<<<dim3((NPN + 3) / 4, 3), 256, 0, stream>>>(aa);
    cur = nxt;
  }

  k_invnorm<<<(ND + NCN + 3) / 4, 256, 0, stream>>>(xdb[cur], xcb[cur], invd, invc);
  for (int c0 = 0; c0 < NB; c0 += CH) {
    int cn = (NB - c0 < CH) ? (NB - c0) : CH;
    k_make_hid<<<((size_t)cn * 48 + 255) / 256, 256, 0, stream>>>(
        xdb[cur], xcb[cur], invd, invc, drug1, drug2, cellb, hid, c0, cn);
    k_gemm_bf<<<dim3((cn + 127) / 128, 6), 256, 0, stream>>>(hid, W1t, h1, cn, 768, 384, b1, 1);
    k_gemm_bf<<<dim3((cn + 127) / 128, 2), 256, 0, stream>>>(h1, W2t, h2, cn, 256, 768, b2, 1);
    k_mlp3<<<(cn + 3) / 4, 256, 0, stream>>>(h2, W3, b3, out, cn, c0);
  }
}